// Round 9
// baseline (203.998 us; speedup 1.0000x reference)
//
#include <hip/hip_runtime.h>
#include <math.h>

#define Bsz 128
#define Usz 16
#define Dsz 256
#define Nsz 1024
#define Osz 256
#define BK  64
#define LDT 72   // fallback-path LDS row stride (u16)

typedef __attribute__((ext_vector_type(2))) unsigned int u32x2;
typedef __attribute__((ext_vector_type(4))) unsigned int u32x4;
typedef __attribute__((ext_vector_type(4))) float f32x4;
typedef __attribute__((ext_vector_type(8))) short bf16x8;

__device__ __forceinline__ unsigned int fbits(float f) {
    union { float f; unsigned int u; } v; v.f = f; return v.u;
}
// pack two f32 -> (bf16(hi)<<16)|bf16(lo) by truncation: 1 v_perm_b32
__device__ __forceinline__ unsigned int pk(float lo, float hi) {
    return __builtin_amdgcn_perm(fbits(hi), fbits(lo), 0x07060302u);
}
__device__ __forceinline__ unsigned short bf16t(float f) {
    return (unsigned short)(fbits(f) >> 16);
}

// fallback-path barrier without vmcnt drain (v4-verified)
__device__ __forceinline__ void sync_nodrain() {
    __builtin_amdgcn_sched_barrier(0);
    asm volatile("s_waitcnt lgkmcnt(0)");
    __builtin_amdgcn_sched_barrier(0);
    __builtin_amdgcn_s_barrier();
    __builtin_amdgcn_sched_barrier(0);
}

// ---------------- lr = softmax_u(X·alr / T) ----------------
__global__ __launch_bounds__(256)
void lr_kernel(const float* __restrict__ X, const float* __restrict__ alr,
               const float* __restrict__ temp, float* __restrict__ lr)
{
    const int b = blockIdx.x;
    const int t = threadIdx.x;
    const int u = t >> 4;
    const int l = t & 15;
    const f32x4* xp = (const f32x4*)(X + ((size_t)b * Usz + u) * Dsz + l * 16);
    const f32x4* ap = (const f32x4*)(alr + (size_t)u * Dsz + l * 16);
    float s = 0.f;
    #pragma unroll
    for (int j = 0; j < 4; j++) {
        const f32x4 xv = xp[j], av = ap[j];
        s += xv[0]*av[0] + xv[1]*av[1] + xv[2]*av[2] + xv[3]*av[3];
    }
    s += __shfl_down(s, 8, 16);
    s += __shfl_down(s, 4, 16);
    s += __shfl_down(s, 2, 16);
    s += __shfl_down(s, 1, 16);
    __shared__ float logits[16];
    if (l == 0) logits[u] = s;
    __syncthreads();
    if (t < 16) {
        const float T = temp[0];
        float m = -1e30f;
        #pragma unroll
        for (int i = 0; i < 16; i++) m = fmaxf(m, logits[i] / T);
        float sum = 0.f;
        #pragma unroll
        for (int i = 0; i < 16; i++) sum += expf(logits[i] / T - m);
        lr[(size_t)b * Usz + t] = expf(logits[t] / T - m) / sum;
    }
}

// ================= NEW PATH: fragment-linear bf16 pre-packing =================
// Fragment layout (bf16): elem offset of (u, tile, s, kgl, l16, j) =
//   ((((u*T + tile)*S + s)*4 + kgl)*16 + l16)*8 + j
// A wave reading (tile, s) with per-lane (kgl=lane>>4, l16=lane&15) gets a
// CONTIGUOUS 1KB dwordx4 load. tile = 16 rows (A: m-tile; B: n-tile).

// ---- pack [X|state] -> Abf (T=8 m-tiles, S=40) ----
__global__ __launch_bounds__(256)
void pack_A(const float* __restrict__ X, const float* __restrict__ state,
            unsigned short* __restrict__ Abf)
{
    const int t = blockIdx.x * 256 + threadIdx.x;   // 128*16*160 = 327680
    const int kq = t % 160;                          // 32B k-quantum (8 floats)
    const int mu = t / 160;                          // m*16+u
    const int u = mu & 15, m = mu >> 4;
    const float* sp = (kq < 32)
        ? X     + (size_t)mu * Dsz + kq * 8
        : state + (size_t)mu * Nsz + (kq - 32) * 8;
    const f32x4 v0 = *(const f32x4*)sp;
    const f32x4 v1 = *(const f32x4*)(sp + 4);
    u32x4 w;
    w[0]=pk(v0[0],v0[1]); w[1]=pk(v0[2],v0[3]); w[2]=pk(v1[0],v1[1]); w[3]=pk(v1[2],v1[3]);
    *(u32x4*)(Abf + (size_t)(u*8 + (m>>4))*20480 + (kq>>2)*512 + (kq&3)*128 + (m&15)*8) = w;
}

// ---- pack out0 (new_state) -> NsP (T=8, S=32) ----
__global__ __launch_bounds__(256)
void pack_ns(const float* __restrict__ ns, unsigned short* __restrict__ NsP)
{
    const int t = blockIdx.x * 256 + threadIdx.x;   // 128*16*128 = 262144
    const int kq = t & 127;
    const int mu = t >> 7;
    const int u = mu & 15, m = mu >> 4;
    const float* sp = ns + (size_t)mu * Nsz + kq * 8;
    const f32x4 v0 = *(const f32x4*)sp;
    const f32x4 v1 = *(const f32x4*)(sp + 4);
    u32x4 w;
    w[0]=pk(v0[0],v0[1]); w[1]=pk(v0[2],v0[3]); w[2]=pk(v1[0],v1[1]); w[3]=pk(v1[2],v1[3]);
    *(u32x4*)(NsP + (size_t)(u*8 + (m>>4))*16384 + (kq>>2)*512 + (kq&3)*128 + (m&15)*8) = w;
}

// ---- weights [k][n] -> frag-linear bf16 [n-tile][s][kgl][l16][8k] ----
// 64k x 64n tile per block via LDS transpose. Rows k<KA from srcA, else srcB
// scaled by scale[u]. Reads coalesced (f32x4 along n); writes contiguous 1KB.
__global__ __launch_bounds__(256)
void prep_w(const float* __restrict__ srcA, const float* __restrict__ srcB,
            const float* __restrict__ scale, unsigned short* __restrict__ dst,
            int KA, int Ktot, int N, int S, int Tn)
{
    const int nblkN = N >> 6;
    const int per_u = (Ktot >> 6) * nblkN;
    const int bid = blockIdx.x;
    const int u   = bid / per_u;
    const int rem = bid % per_u;
    const int kt  = rem / nblkN;
    const int nt4 = rem % nblkN;

    const int t  = threadIdx.x;
    const int kr = t >> 4;
    const int nc = (t & 15) * 4;
    const int n0 = nt4 * 64;

    const float sc = scale ? scale[u] : 1.f;

    __shared__ float tl[64][68];

    #pragma unroll
    for (int r = 0; r < 4; r++) {
        const int kl = kr + r * 16;
        const int k  = kt * 64 + kl;
        const float* sp = (k < KA)
            ? srcA + ((size_t)u * KA + k) * N + n0 + nc
            : srcB + ((size_t)u * (Ktot - KA) + (k - KA)) * N + n0 + nc;
        f32x4 v = *(const f32x4*)sp;
        if (k >= KA) v *= sc;
        *(f32x4*)&tl[kl][nc] = v;
    }
    __syncthreads();
    #pragma unroll
    for (int fi = 0; fi < 2; fi++) {
        const int f   = t + fi * 256;
        const int l   = f & 15;
        const int g   = (f >> 4) & 7;
        const int ntl = f >> 7;
        float x[8];
        #pragma unroll
        for (int i = 0; i < 8; i++) x[i] = tl[g*8 + i][ntl*16 + l];
        u32x4 w;
        w[0]=pk(x[0],x[1]); w[1]=pk(x[2],x[3]); w[2]=pk(x[4],x[5]); w[3]=pk(x[6],x[7]);
        const int tn = nt4*4 + ntl;
        const int s  = kt*2 + (g>>2);
        *(u32x4*)(dst + ((size_t)(u*Tn + tn)*S + s)*512 + (g&3)*128 + l*8) = w;
    }
}

// ---- state GEMM v9: LDS-free, barrier-free register stream ----
// grid 512 = nt2(32) x u16 (u inner). Block 512 thr = 8 waves (wm4 x wn2):
// wave = 32m(2 m-tiles) x 16n. Per k32-step: 3 contiguous-1KB loads + 2 MFMA,
// 40 steps fully unrolled, 3-stage register pipeline. Waves free-run.
__global__ __launch_bounds__(512, 4)
void state_gemm_reg(const float* __restrict__ state,
                    const unsigned short* __restrict__ Abf,
                    const unsigned short* __restrict__ Bp,
                    const float* __restrict__ bias, const float* __restrict__ lr,
                    float* __restrict__ out0)
{
    const int id  = blockIdx.x;
    const int u   = id & 15;
    const int nt2 = id >> 4;

    const int tid = threadIdx.x;
    const int wave = tid >> 6, lane = tid & 63;
    const int l16 = lane & 15, kgl = lane >> 4;
    const int wm = wave & 3, wn = wave >> 2;
    const int mt0 = wm * 2;
    const int tn  = nt2 * 2 + wn;

    const unsigned short* pa0 = Abf + (size_t)(u*8 + mt0)    *20480 + kgl*128 + l16*8;
    const unsigned short* pa1 = Abf + (size_t)(u*8 + mt0 + 1)*20480 + kgl*128 + l16*8;
    const unsigned short* pb  = Bp  + (size_t)(u*64 + tn)    *20480 + kgl*128 + l16*8;

    bf16x8 a0[3], a1[3], bb[3];
    f32x4 acc0 = {}, acc1 = {};

    a0[0] = *(const bf16x8*)(pa0);        a1[0] = *(const bf16x8*)(pa1);        bb[0] = *(const bf16x8*)(pb);
    a0[1] = *(const bf16x8*)(pa0 + 512);  a1[1] = *(const bf16x8*)(pa1 + 512);  bb[1] = *(const bf16x8*)(pb + 512);

    #pragma unroll
    for (int s = 0; s < 40; s++) {
        const int st = s % 3, nx = (s + 2) % 3;     // constants after unroll
        if (s + 2 < 40) {
            a0[nx] = *(const bf16x8*)(pa0 + (size_t)(s + 2) * 512);
            a1[nx] = *(const bf16x8*)(pa1 + (size_t)(s + 2) * 512);
            bb[nx] = *(const bf16x8*)(pb  + (size_t)(s + 2) * 512);
        }
        acc0 = __builtin_amdgcn_mfma_f32_16x16x32_bf16(a0[st], bb[st], acc0, 0, 0, 0);
        acc1 = __builtin_amdgcn_mfma_f32_16x16x32_bf16(a1[st], bb[st], acc1, 0, 0, 0);
    }

    // C/D layout: col=lane&15, row=(lane>>4)*4+reg (HW-verified)
    const int gcol = tn * 16 + l16;
    const float bi = bias[u * Nsz + gcol];
    #pragma unroll
    for (int mi = 0; mi < 2; mi++) {
        const f32x4 a = mi ? acc1 : acc0;
        #pragma unroll
        for (int rg = 0; rg < 4; rg++) {
            const int grow = (mt0 + mi) * 16 + kgl * 4 + rg;
            const size_t idx = ((size_t)grow * Usz + u) * Nsz + gcol;
            const float th = tanhf(a[rg] + bi);
            const float lv = lr[grow * Usz + u];
            out0[idx] = (1.f - lv) * state[idx] + lv * th;
        }
    }
}

// ---- out GEMM v9: same register-stream structure, ks4 split-K ----
__global__ __launch_bounds__(512, 4)
void out_gemm_reg(const unsigned short* __restrict__ NsP,
                  const unsigned short* __restrict__ Wp,
                  float* __restrict__ part)
{
    const int id = blockIdx.x;    // 512 = ks4 x u16 x ot8 (ot inner)
    const int ot = id & 7;
    const int u  = (id >> 3) & 15;
    const int ks = id >> 7;
    const int sb = ks * 8;

    const int tid = threadIdx.x;
    const int wave = tid >> 6, lane = tid & 63;
    const int l16 = lane & 15, kgl = lane >> 4;
    const int wm = wave & 3, wn = wave >> 2;
    const int mt0 = wm * 2;
    const int tn  = ot * 2 + wn;

    const unsigned short* pa0 = NsP + (size_t)(u*8 + mt0)    *16384 + (size_t)sb*512 + kgl*128 + l16*8;
    const unsigned short* pa1 = NsP + (size_t)(u*8 + mt0 + 1)*16384 + (size_t)sb*512 + kgl*128 + l16*8;
    const unsigned short* pb  = Wp  + (size_t)(u*16 + tn)    *16384 + (size_t)sb*512 + kgl*128 + l16*8;

    bf16x8 a0[3], a1[3], bb[3];
    f32x4 acc0 = {}, acc1 = {};

    a0[0] = *(const bf16x8*)(pa0);        a1[0] = *(const bf16x8*)(pa1);        bb[0] = *(const bf16x8*)(pb);
    a0[1] = *(const bf16x8*)(pa0 + 512);  a1[1] = *(const bf16x8*)(pa1 + 512);  bb[1] = *(const bf16x8*)(pb + 512);

    #pragma unroll
    for (int s = 0; s < 8; s++) {
        const int st = s % 3, nx = (s + 2) % 3;
        if (s + 2 < 8) {
            a0[nx] = *(const bf16x8*)(pa0 + (size_t)(s + 2) * 512);
            a1[nx] = *(const bf16x8*)(pa1 + (size_t)(s + 2) * 512);
            bb[nx] = *(const bf16x8*)(pb  + (size_t)(s + 2) * 512);
        }
        acc0 = __builtin_amdgcn_mfma_f32_16x16x32_bf16(a0[st], bb[st], acc0, 0, 0, 0);
        acc1 = __builtin_amdgcn_mfma_f32_16x16x32_bf16(a1[st], bb[st], acc1, 0, 0, 0);
    }

    const int gcol = tn * 16 + l16;
    #pragma unroll
    for (int mi = 0; mi < 2; mi++) {
        const f32x4 a = mi ? acc1 : acc0;
        #pragma unroll
        for (int rg = 0; rg < 4; rg++) {
            const int grow = (mt0 + mi) * 16 + kgl * 4 + rg;
            part[(((size_t)ks * 16 + u) * 128 + grow) * 256 + gcol] = a[rg];
        }
    }
}

// ---- sum 4 out-partials -> out1 ----
__global__ __launch_bounds__(256)
void out_reduce(const float* __restrict__ part, float* __restrict__ out1)
{
    const size_t i = (size_t)blockIdx.x * 256 + threadIdx.x;
    const size_t base = i * 4;
    const int m = (int)(base >> 12);
    const int u = (int)((base >> 8) & 15);
    const int o = (int)(base & 255);

    const size_t pb = ((size_t)u * 128 + m) * 256 + o;
    const size_t slab = (size_t)16 * 128 * 256;
    f32x4 s = *(const f32x4*)(part + pb);
    s += *(const f32x4*)(part + pb + slab);
    s += *(const f32x4*)(part + pb + 2 * slab);
    s += *(const f32x4*)(part + pb + 3 * slab);
    *(f32x4*)(out1 + base) = s;
}

// ===================== FALLBACK PATH (v8, ws too small) =====================
__global__ __launch_bounds__(512)
void state_gemm_fb(const float* __restrict__ X, const float* __restrict__ state,
                   const float* __restrict__ W, const float* __restrict__ Win,
                   const float* __restrict__ bias, const float* __restrict__ sr,
                   const float* __restrict__ lr, float* __restrict__ out0)
{
    const int id = blockIdx.x;
    const int u  = id & 15;
    const int nt = id >> 4;

    const int tid  = threadIdx.x;
    const int wave = tid >> 6;
    const int lane = tid & 63;
    const int l16  = lane & 15, kgl = lane >> 4;
    const int wm = wave & 3, wn = wave >> 2;

    __shared__ unsigned short As[2][128 * LDT];
    __shared__ unsigned short Bs[2][32 * LDT];

    const float sru = sr[u];
    const int col0 = nt * 32;

    const int rA = tid >> 2;
    const int cA = (tid & 3) * 16;
    const int kB = tid >> 3;
    const int nB = (tid & 7) * 4;
    const int gB = kB >> 3, kL = kB & 7;

    f32x4 rAE[4], rAO[4];
    f32x4 rBE,    rBO;

    auto ldA = [&](int s, f32x4 (&ra)[4]) {
        const int k0 = s * BK;
        const float* base = (k0 < Dsz)
            ? X     + ((size_t)rA * Usz + u) * Dsz + k0 + cA
            : state + ((size_t)rA * Usz + u) * Nsz + (k0 - Dsz) + cA;
        #pragma unroll
        for (int j = 0; j < 4; j++) ra[j] = *(const f32x4*)(base + 4 * j);
    };
    auto ldB = [&](int s, f32x4& rb) {
        const int k0 = s * BK;
        const float* base = (k0 < Dsz)
            ? Win + (size_t)u * Dsz * Nsz + (size_t)(k0 + kB) * Nsz + col0 + nB
            : W   + (size_t)u * Nsz * Nsz + (size_t)(k0 - Dsz + kB) * Nsz + col0 + nB;
        rb = *(const f32x4*)base;
    };
    auto wrA = [&](int p, f32x4 (&ra)[4]) {
        u32x4 w0, w1;
        w0[0] = pk(ra[0][0], ra[0][1]); w0[1] = pk(ra[0][2], ra[0][3]);
        w0[2] = pk(ra[1][0], ra[1][1]); w0[3] = pk(ra[1][2], ra[1][3]);
        w1[0] = pk(ra[2][0], ra[2][1]); w1[1] = pk(ra[2][2], ra[2][3]);
        w1[2] = pk(ra[3][0], ra[3][1]); w1[3] = pk(ra[3][2], ra[3][3]);
        *(u32x4*)&As[p][rA * LDT + cA]     = w0;
        *(u32x4*)&As[p][rA * LDT + cA + 8] = w1;
    };
    auto wrB = [&](int p, f32x4& rb, float sc) {
        const int c = tid & 7;
        const int go = ((gB ^ c) << 3) + kL;
        #pragma unroll
        for (int e = 0; e < 4; e++)
            Bs[p][(nB + e) * LDT + go] = bf16t(rb[e] * sc);
    };
    auto rdB = [&](int p, int kk) -> bf16x8 {
        const int n = wn * 16 + l16;
        const int go = (((kk * 4 + kgl) ^ (n >> 2)) << 3);
        return *(const bf16x8*)&Bs[p][n * LDT + go];
    };

    f32x4 acc[2] = {};
    auto comp = [&](int p) {
        #pragma unroll
        for (int kk = 0; kk < 2; kk++) {
            const bf16x8 bf = rdB(p, kk);
            #pragma unroll
            for (int mi = 0; mi < 2; mi++) {
                const bf16x8 af = *(const bf16x8*)&As[p][(wm * 32 + mi * 16 + l16) * LDT + kk * 32 + kgl * 8];
                acc[mi] = __builtin_amdgcn_mfma_f32_16x16x32_bf16(af, bf, acc[mi], 0, 0, 0);
            }
        }
    };
    auto scB = [&](int s) -> float { return (s * BK < Dsz) ? 1.f : sru; };

    ldA(0, rAE); ldB(0, rBE);
    ldA(1, rAO); ldB(1, rBO);
    wrA(0, rAE); wrB(0, rBE, scB(0));
    sync_nodrain();

    for (int s2 = 0; s2 < 10; s2++) {
        const int s = 2 * s2;
        if (s + 2 < 20) { ldA(s + 2, rAE); ldB(s + 2, rBE); }
        wrA(1, rAO); wrB(1, rBO, scB(s + 1));
        comp(0);
        sync_nodrain();
        if (s + 3 < 20) { ldA(s + 3, rAO); ldB(s + 3, rBO); }
        if (s + 2 < 20) { wrA(0, rAE); wrB(0, rBE, scB(s + 2)); }
        comp(1);
        sync_nodrain();
    }

    const int gcol = col0 + wn * 16 + l16;
    const float bi = bias[u * Nsz + gcol];
    #pragma unroll
    for (int mi = 0; mi < 2; mi++) {
        #pragma unroll
        for (int rg = 0; rg < 4; rg++) {
            const int grow = wm * 32 + mi * 16 + kgl * 4 + rg;
            const size_t idx = ((size_t)grow * Usz + u) * Nsz + gcol;
            const float th = tanhf(acc[mi][rg] + bi);
            const float lv = lr[grow * Usz + u];
            out0[idx] = (1.f - lv) * state[idx] + lv * th;
        }
    }
}

__global__ __launch_bounds__(512)
void out_gemm_fb(const float* __restrict__ ns, const float* __restrict__ Wout,
                 float* __restrict__ dst, int nsteps, int partial)
{
    const int id = blockIdx.x;
    const int ot = id & 7;
    const int u  = (id >> 3) & 15;
    const int ks = id >> 7;
    const int kbase = ks * nsteps * BK;

    const int tid  = threadIdx.x;
    const int wave = tid >> 6;
    const int lane = tid & 63;
    const int l16  = lane & 15, kgl = lane >> 4;
    const int wm = wave & 3, wn = wave >> 2;

    __shared__ unsigned short As[2][128 * LDT];
    __shared__ unsigned short Bs[2][32 * LDT];

    const int col0 = ot * 32;
    const int rA = tid >> 2;
    const int cA = (tid & 3) * 16;
    const int kB = tid >> 3;
    const int nB = (tid & 7) * 4;
    const int gB = kB >> 3, kL = kB & 7;

    f32x4 rAE[4], rAO[4];
    f32x4 rBE,    rBO;

    auto ldA = [&](int s, f32x4 (&ra)[4]) {
        const float* base = ns + ((size_t)rA * Usz + u) * Nsz + kbase + s * BK + cA;
        #pragma unroll
        for (int j = 0; j < 4; j++) ra[j] = *(const f32x4*)(base + 4 * j);
    };
    auto ldB = [&](int s, f32x4& rb) {
        rb = *(const f32x4*)(Wout + (size_t)u * Nsz * Osz
                             + (size_t)(kbase + s * BK + kB) * Osz + col0 + nB);
    };
    auto wrA = [&](int p, f32x4 (&ra)[4]) {
        u32x4 w0, w1;
        w0[0] = pk(ra[0][0], ra[0][1]); w0[1] = pk(ra[0][2], ra[0][3]);
        w0[2] = pk(ra[1][0], ra[1][1]); w0[3] = pk(ra[1][2], ra[1][3]);
        w1[0] = pk(ra[2][0], ra[2][1]); w1[1] = pk(ra[2][2], ra[2][3]);
        w1[2] = pk(ra[3][0], ra[3][1]); w1[3] = pk(ra[3][2], ra[3][3]);
        *(u32x4*)&As[p][rA * LDT + cA]     = w0;
        *(u32x4*)&As[p][rA * LDT + cA + 8] = w1;
    };
    auto wrB = [&](int p, f32x4& rb) {
        const int c = tid & 7;
        const int go = ((gB ^ c) << 3) + kL;
        #pragma unroll
        for (int e = 0; e < 4; e++)
            Bs[p][(nB + e) * LDT + go] = bf16t(rb[e]);
    };
    auto rdB = [&](int p, int kk) -> bf16x8 {
        const int n = wn * 16 + l16;
        const int go = (((kk * 4 + kgl) ^ (n >> 2)) << 3);
        return *(const bf16x8*)&Bs[p][n * LDT + go];
    };

    f32x4 acc[2] = {};
    auto comp = [&](int p) {
        #pragma unroll
        for (int kk = 0; kk < 2; kk++) {
            const bf16x8 bf = rdB(p, kk);
            #pragma unroll
            for (int mi = 0; mi < 2; mi++) {
                const bf16x8 af = *(const bf16x8*)&As[p][(wm * 32 + mi * 16 + l16) * LDT + kk * 32 + kgl * 8];
                acc[mi] = __builtin_amdgcn_mfma_f32_16x16x32_bf16(af, bf, acc[mi], 0, 0, 0);
            }
        }
    };

    ldA(0, rAE); ldB(0, rBE);
    ldA(1, rAO); ldB(1, rBO);
    wrA(0, rAE); wrB(0, rBE);
    sync_nodrain();

    for (int s2 = 0; s2 < nsteps / 2; s2++) {
        const int s = 2 * s2;
        if (s + 2 < nsteps) { ldA(s + 2, rAE); ldB(s + 2, rBE); }
        wrA(1, rAO); wrB(1, rBO);
        comp(0);
        sync_nodrain();
        if (s + 3 < nsteps) { ldA(s + 3, rAO); ldB(s + 3, rBO); }
        if (s + 2 < nsteps) { wrA(0, rAE); wrB(0, rBE); }
        comp(1);
        sync_nodrain();
    }

    const int gcol = col0 + wn * 16 + l16;
    #pragma unroll
    for (int mi = 0; mi < 2; mi++) {
        #pragma unroll
        for (int rg = 0; rg < 4; rg++) {
            const int grow = wm * 32 + mi * 16 + kgl * 4 + rg;
            if (partial)
                dst[(((size_t)ks * 16 + u) * 128 + grow) * 256 + gcol] = acc[mi][rg];
            else
                dst[((size_t)grow * Usz + u) * Osz + gcol] = acc[mi][rg];
        }
    }
}

extern "C" void kernel_launch(void* const* d_in, const int* in_sizes, int n_in,
                              void* d_out, int out_size, void* d_ws, size_t ws_size,
                              hipStream_t stream)
{
    (void)in_sizes; (void)n_in; (void)out_size;
    const float* X     = (const float*)d_in[0];
    const float* state = (const float*)d_in[1];
    const float* W     = (const float*)d_in[2];
    const float* Win   = (const float*)d_in[3];
    const float* bias  = (const float*)d_in[4];
    const float* Wout  = (const float*)d_in[5];
    const float* sr    = (const float*)d_in[6];
    const float* alr   = (const float*)d_in[7];
    const float* temp  = (const float*)d_in[8];

    float* out0 = (float*)d_out;                      // (B,U,N)
    float* out1 = out0 + (size_t)Bsz * Usz * Nsz;     // (B,U,O)
    float* lr   = (float*)d_ws;                       // 8 KB

    const size_t p_off    = 8192;
    const size_t p_bytes  = (size_t)4 * 16 * 128 * 256 * 4;        // 8 MiB
    const size_t bp_off   = p_off + p_bytes;
    const size_t bp_bytes = (size_t)16 * 1280 * 1024 * 2;          // 40 MiB
    const size_t wo_off   = bp_off + bp_bytes;
    const size_t wo_bytes = (size_t)16 * 1024 * 256 * 2;           // 8 MiB
    const size_t ab_off   = wo_off + wo_bytes;
    const size_t ab_bytes = (size_t)128 * 16 * 1280 * 2;           // 5 MiB
    const size_t ns_off   = ab_off + ab_bytes;
    const size_t ns_bytes = (size_t)128 * 16 * 1024 * 2;           // 4 MiB
    const size_t need     = ns_off + ns_bytes;                     // ~65 MiB

    lr_kernel<<<Bsz, 256, 0, stream>>>(X, alr, temp, lr);

    if (ws_size >= need) {
        float*          part = (float*)((char*)d_ws + p_off);
        unsigned short* Bp   = (unsigned short*)((char*)d_ws + bp_off);
        unsigned short* Wp   = (unsigned short*)((char*)d_ws + wo_off);
        unsigned short* Abf  = (unsigned short*)((char*)d_ws + ab_off);
        unsigned short* NsP  = (unsigned short*)((char*)d_ws + ns_off);

        prep_w<<<5120, 256, 0, stream>>>(Win, W, sr, Bp, Dsz, 1280, Nsz, 40, 64);
        prep_w<<<1024, 256, 0, stream>>>(Wout, Wout, nullptr, Wp, Nsz, Nsz, Osz, 32, 16);
        pack_A<<<1280, 256, 0, stream>>>(X, state, Abf);
        state_gemm_reg<<<512, 512, 0, stream>>>(state, Abf, Bp, bias, lr, out0);
        pack_ns<<<1024, 256, 0, stream>>>(out0, NsP);
        out_gemm_reg<<<512, 512, 0, stream>>>(NsP, Wp, part);
        out_reduce<<<512, 256, 0, stream>>>(part, out1);
    } else if (ws_size >= p_off + p_bytes) {
        float* part = (float*)((char*)d_ws + p_off);
        state_gemm_fb<<<512, 512, 0, stream>>>(X, state, W, Win, bias, sr, lr, out0);
        out_gemm_fb<<<512, 512, 0, stream>>>(out0, Wout, part, 4, 1);
        out_reduce<<<512, 256, 0, stream>>>(part, out1);
    } else {
        state_gemm_fb<<<512, 512, 0, stream>>>(X, state, W, Win, bias, sr, lr, out0);
        out_gemm_fb<<<128, 512, 0, stream>>>(out0, Wout, out1, 16, 0);
    }
}

// Round 10
// 200.145 us; speedup vs baseline: 1.0193x; 1.0193x over previous
//
#include <hip/hip_runtime.h>
#include <math.h>

#define Bsz 128
#define Usz 16
#define Dsz 256
#define Nsz 1024
#define Osz 256
#define BK  64
#define LDT 72   // v8-path LDS row stride (u16)

typedef __attribute__((ext_vector_type(2))) unsigned int u32x2;
typedef __attribute__((ext_vector_type(4))) unsigned int u32x4;
typedef __attribute__((ext_vector_type(4))) float f32x4;
typedef __attribute__((ext_vector_type(8))) short bf16x8;

__device__ __forceinline__ unsigned int fbits(float f) {
    union { float f; unsigned int u; } v; v.f = f; return v.u;
}
// pack two f32 -> (bf16(hi)<<16)|bf16(lo) by truncation: 1 v_perm_b32
__device__ __forceinline__ unsigned int pk(float lo, float hi) {
    return __builtin_amdgcn_perm(fbits(hi), fbits(lo), 0x07060302u);
}
__device__ __forceinline__ unsigned short bf16t(float f) {
    return (unsigned short)(fbits(f) >> 16);
}

// Barrier without the vmcnt(0) drain (v4-verified +18%). Un-clobbered asm
// (v3: "memory" clobber re-introduces the drain), sched_barrier fences.
__device__ __forceinline__ void sync_nodrain() {
    __builtin_amdgcn_sched_barrier(0);
    asm volatile("s_waitcnt lgkmcnt(0)");
    __builtin_amdgcn_sched_barrier(0);
    __builtin_amdgcn_s_barrier();
    __builtin_amdgcn_sched_barrier(0);
}

// ---------------- lr = softmax_u(X·alr / T) ----------------
__global__ __launch_bounds__(256)
void lr_kernel(const float* __restrict__ X, const float* __restrict__ alr,
               const float* __restrict__ temp, float* __restrict__ lr)
{
    const int b = blockIdx.x;
    const int t = threadIdx.x;
    const int u = t >> 4;
    const int l = t & 15;
    const f32x4* xp = (const f32x4*)(X + ((size_t)b * Usz + u) * Dsz + l * 16);
    const f32x4* ap = (const f32x4*)(alr + (size_t)u * Dsz + l * 16);
    float s = 0.f;
    #pragma unroll
    for (int j = 0; j < 4; j++) {
        const f32x4 xv = xp[j], av = ap[j];
        s += xv[0]*av[0] + xv[1]*av[1] + xv[2]*av[2] + xv[3]*av[3];
    }
    s += __shfl_down(s, 8, 16);
    s += __shfl_down(s, 4, 16);
    s += __shfl_down(s, 2, 16);
    s += __shfl_down(s, 1, 16);
    __shared__ float logits[16];
    if (l == 0) logits[u] = s;
    __syncthreads();
    if (t < 16) {
        const float T = temp[0];
        float m = -1e30f;
        #pragma unroll
        for (int i = 0; i < 16; i++) m = fmaxf(m, logits[i] / T);
        float sum = 0.f;
        #pragma unroll
        for (int i = 0; i < 16; i++) sum += expf(logits[i] / T - m);
        lr[(size_t)b * Usz + t] = expf(logits[t] / T - m) / sum;
    }
}

// ---- state GEMM v10: split-K (ks2), 4 blocks/CU via exact-40KB LDS ----
// Model (fits v0-v8): T = seq-steps/CU x ~2.5us step latency. ks2 -> 1024
// blocks x 10 steps; LDS trimmed 45->40KB (A unpadded [128][64] with XOR
// group-swizzle slot = g ^ (r&7) instead of pad; B stride 64 with v8 XOR)
// -> 4 blocks/CU co-resident -> 10 sequential latency windows (was 20).
// Writes raw f32 partials; epilogue fused in state_ep.
__global__ __launch_bounds__(512, 8)
void state_gemm_sk(const float* __restrict__ X, const float* __restrict__ state,
                   const float* __restrict__ W, const float* __restrict__ Win,
                   const float* __restrict__ sr, float* __restrict__ part2)
{
    const int id = blockIdx.x;        // 1024 = ks2 x nt32 x u16 (u inner)
    const int u  = id & 15;
    const int nt = (id >> 4) & 31;
    const int ks = id >> 9;
    const int kbase = ks * 640;       // 10 steps of BK=64

    const int tid  = threadIdx.x;     // 0..511
    const int wave = tid >> 6;
    const int lane = tid & 63;
    const int l16  = lane & 15, kgl = lane >> 4;
    const int wm = wave & 3, wn = wave >> 2;

    __shared__ unsigned short As[2][128 * 64];   // 32 KB
    __shared__ unsigned short Bs[2][32 * 64];    //  8 KB  (total 40 KB)

    const float sru = sr[u];
    const int col0 = nt * 32;

    // A staging: thread -> row rA = tid>>2 (0..127), k-span cA..cA+15
    const int rA = tid >> 2;
    const int cA = (tid & 3) * 16;
    const int g0 = (tid & 3) * 2;           // logical 8-col group of cA
    const int sw = rA & 7;                  // A swizzle key
    // B staging: thread -> k = kB (0..63), n = nB..nB+3
    const int kB = tid >> 3;
    const int nB = (tid & 7) * 4;
    const int gB = kB >> 3, kL = kB & 7;

    f32x4 rAE[4], rAO[4];
    f32x4 rBE,    rBO;

    auto ldA = [&](int s, f32x4 (&ra)[4]) {
        const int k0 = kbase + s * BK;
        const float* base = (k0 < Dsz)
            ? X     + ((size_t)rA * Usz + u) * Dsz + k0 + cA
            : state + ((size_t)rA * Usz + u) * Nsz + (k0 - Dsz) + cA;
        #pragma unroll
        for (int j = 0; j < 4; j++) ra[j] = *(const f32x4*)(base + 4 * j);
    };
    auto ldB = [&](int s, f32x4& rb) {
        const int k0 = kbase + s * BK;
        const float* base = (k0 < Dsz)
            ? Win + (size_t)u * Dsz * Nsz + (size_t)(k0 + kB) * Nsz + col0 + nB
            : W   + (size_t)u * Nsz * Nsz + (size_t)(k0 - Dsz + kB) * Nsz + col0 + nB;
        rb = *(const f32x4*)base;
    };
    // logical col-group g stored at slot g^(rA&7); two b128 per thread
    auto wrA = [&](int p, f32x4 (&ra)[4]) {
        u32x4 w0, w1;
        w0[0] = pk(ra[0][0], ra[0][1]); w0[1] = pk(ra[0][2], ra[0][3]);
        w0[2] = pk(ra[1][0], ra[1][1]); w0[3] = pk(ra[1][2], ra[1][3]);
        w1[0] = pk(ra[2][0], ra[2][1]); w1[1] = pk(ra[2][2], ra[2][3]);
        w1[2] = pk(ra[3][0], ra[3][1]); w1[3] = pk(ra[3][2], ra[3][3]);
        *(u32x4*)&As[p][rA * 64 + ((g0       ^ sw) << 3)] = w0;
        *(u32x4*)&As[p][rA * 64 + (((g0 | 1) ^ sw) << 3)] = w1;
    };
    auto wrB = [&](int p, f32x4& rb, float sc) {
        const int c = tid & 7;
        const int go = ((gB ^ c) << 3) + kL;
        #pragma unroll
        for (int e = 0; e < 4; e++)
            Bs[p][(nB + e) * 64 + go] = bf16t(rb[e] * sc);
    };
    auto rdB = [&](int p, int kk) -> bf16x8 {
        const int n = wn * 16 + l16;
        const int go = (((kk * 4 + kgl) ^ (n >> 2)) << 3);
        return *(const bf16x8*)&Bs[p][n * 64 + go];
    };

    f32x4 acc[2] = {};
    auto comp = [&](int p) {
        #pragma unroll
        for (int kk = 0; kk < 2; kk++) {
            const bf16x8 bf = rdB(p, kk);
            #pragma unroll
            for (int mi = 0; mi < 2; mi++) {
                const int r = wm * 32 + mi * 16 + l16;
                const bf16x8 af = *(const bf16x8*)&As[p][r * 64 + (((kk * 4 + kgl) ^ (r & 7)) << 3)];
                acc[mi] = __builtin_amdgcn_mfma_f32_16x16x32_bf16(af, bf, acc[mi], 0, 0, 0);
            }
        }
    };
    auto scB = [&](int s) -> float { return (kbase + s * BK < Dsz) ? 1.f : sru; };

    ldA(0, rAE); ldB(0, rBE);
    ldA(1, rAO); ldB(1, rBO);
    wrA(0, rAE); wrB(0, rBE, scB(0));
    sync_nodrain();

    for (int s2 = 0; s2 < 5; s2++) {
        const int s = 2 * s2;
        if (s + 2 < 10) { ldA(s + 2, rAE); ldB(s + 2, rBE); }
        wrA(1, rAO); wrB(1, rBO, scB(s + 1));
        comp(0);
        sync_nodrain();
        if (s + 3 < 10) { ldA(s + 3, rAO); ldB(s + 3, rBO); }
        if (s + 2 < 10) { wrA(0, rAE); wrB(0, rBE, scB(s + 2)); }
        comp(1);
        sync_nodrain();
    }

    // raw partial write: part2[ks][m][u][n]
    const int gcol = col0 + wn * 16 + l16;
    float* dst = part2 + (size_t)ks * 128 * Usz * Nsz;
    #pragma unroll
    for (int mi = 0; mi < 2; mi++) {
        #pragma unroll
        for (int rg = 0; rg < 4; rg++) {
            const int grow = wm * 32 + mi * 16 + kgl * 4 + rg;
            dst[((size_t)grow * Usz + u) * Nsz + gcol] = acc[mi][rg];
        }
    }
}

// ---- state epilogue: out0 = (1-lr)*state + lr*tanh(p0+p1+bias) ----
__global__ __launch_bounds__(256)
void state_ep(const float* __restrict__ part2, const float* __restrict__ state,
              const float* __restrict__ bias, const float* __restrict__ lr,
              float* __restrict__ out0)
{
    const size_t i = (size_t)blockIdx.x * 256 + threadIdx.x;   // 0..524287
    const size_t base = i * 4;                  // flat [m][u][n]
    const int m = (int)(i >> 12);
    const int u = (int)((i >> 8) & 15);
    const int n = (int)((i & 255) * 4);

    const size_t slab = (size_t)128 * Usz * Nsz;
    f32x4 s = *(const f32x4*)(part2 + base);
    s += *(const f32x4*)(part2 + base + slab);
    const f32x4 bi = *(const f32x4*)(bias + u * Nsz + n);
    const f32x4 st = *(const f32x4*)(state + base);
    const float lv = lr[m * Usz + u];
    f32x4 o;
    #pragma unroll
    for (int e = 0; e < 4; e++)
        o[e] = (1.f - lv) * st[e] + lv * tanhf(s[e] + bi[e]);
    *(f32x4*)(out0 + base) = o;
}

// ---- out GEMM (v8, unchanged): ns(128xK=1024)·Wout(Kx256), split-K ----
__global__ __launch_bounds__(512)
void out_gemm_fb(const float* __restrict__ ns, const float* __restrict__ Wout,
                 float* __restrict__ dst, int nsteps, int partial)
{
    const int id = blockIdx.x;
    const int ot = id & 7;
    const int u  = (id >> 3) & 15;
    const int ks = id >> 7;
    const int kbase = ks * nsteps * BK;

    const int tid  = threadIdx.x;
    const int wave = tid >> 6;
    const int lane = tid & 63;
    const int l16  = lane & 15, kgl = lane >> 4;
    const int wm = wave & 3, wn = wave >> 2;

    __shared__ unsigned short As[2][128 * LDT];
    __shared__ unsigned short Bs[2][32 * LDT];

    const int col0 = ot * 32;
    const int rA = tid >> 2;
    const int cA = (tid & 3) * 16;
    const int kB = tid >> 3;
    const int nB = (tid & 7) * 4;
    const int gB = kB >> 3, kL = kB & 7;

    f32x4 rAE[4], rAO[4];
    f32x4 rBE,    rBO;

    auto ldA = [&](int s, f32x4 (&ra)[4]) {
        const float* base = ns + ((size_t)rA * Usz + u) * Nsz + kbase + s * BK + cA;
        #pragma unroll
        for (int j = 0; j < 4; j++) ra[j] = *(const f32x4*)(base + 4 * j);
    };
    auto ldB = [&](int s, f32x4& rb) {
        rb = *(const f32x4*)(Wout + (size_t)u * Nsz * Osz
                             + (size_t)(kbase + s * BK + kB) * Osz + col0 + nB);
    };
    auto wrA = [&](int p, f32x4 (&ra)[4]) {
        u32x4 w0, w1;
        w0[0] = pk(ra[0][0], ra[0][1]); w0[1] = pk(ra[0][2], ra[0][3]);
        w0[2] = pk(ra[1][0], ra[1][1]); w0[3] = pk(ra[1][2], ra[1][3]);
        w1[0] = pk(ra[2][0], ra[2][1]); w1[1] = pk(ra[2][2], ra[2][3]);
        w1[2] = pk(ra[3][0], ra[3][1]); w1[3] = pk(ra[3][2], ra[3][3]);
        *(u32x4*)&As[p][rA * LDT + cA]     = w0;
        *(u32x4*)&As[p][rA * LDT + cA + 8] = w1;
    };
    auto wrB = [&](int p, f32x4& rb) {
        const int c = tid & 7;
        const int go = ((gB ^ c) << 3) + kL;
        #pragma unroll
        for (int e = 0; e < 4; e++)
            Bs[p][(nB + e) * LDT + go] = bf16t(rb[e]);
    };
    auto rdB = [&](int p, int kk) -> bf16x8 {
        const int n = wn * 16 + l16;
        const int go = (((kk * 4 + kgl) ^ (n >> 2)) << 3);
        return *(const bf16x8*)&Bs[p][n * LDT + go];
    };

    f32x4 acc[2] = {};
    auto comp = [&](int p) {
        #pragma unroll
        for (int kk = 0; kk < 2; kk++) {
            const bf16x8 bf = rdB(p, kk);
            #pragma unroll
            for (int mi = 0; mi < 2; mi++) {
                const bf16x8 af = *(const bf16x8*)&As[p][(wm * 32 + mi * 16 + l16) * LDT + kk * 32 + kgl * 8];
                acc[mi] = __builtin_amdgcn_mfma_f32_16x16x32_bf16(af, bf, acc[mi], 0, 0, 0);
            }
        }
    };

    ldA(0, rAE); ldB(0, rBE);
    ldA(1, rAO); ldB(1, rBO);
    wrA(0, rAE); wrB(0, rBE);
    sync_nodrain();

    for (int s2 = 0; s2 < nsteps / 2; s2++) {
        const int s = 2 * s2;
        if (s + 2 < nsteps) { ldA(s + 2, rAE); ldB(s + 2, rBE); }
        wrA(1, rAO); wrB(1, rBO);
        comp(0);
        sync_nodrain();
        if (s + 3 < nsteps) { ldA(s + 3, rAO); ldB(s + 3, rBO); }
        if (s + 2 < nsteps) { wrA(0, rAE); wrB(0, rBE); }
        comp(1);
        sync_nodrain();
    }

    const int gcol = col0 + wn * 16 + l16;
    #pragma unroll
    for (int mi = 0; mi < 2; mi++) {
        #pragma unroll
        for (int rg = 0; rg < 4; rg++) {
            const int grow = wm * 32 + mi * 16 + kgl * 4 + rg;
            if (partial)
                dst[(((size_t)ks * 16 + u) * 128 + grow) * 256 + gcol] = acc[mi][rg];
            else
                dst[((size_t)grow * Usz + u) * Osz + gcol] = acc[mi][rg];
        }
    }
}

// ---- sum 4 out-partials -> out1 ----
__global__ __launch_bounds__(256)
void out_reduce(const float* __restrict__ part, float* __restrict__ out1)
{
    const size_t i = (size_t)blockIdx.x * 256 + threadIdx.x;
    const size_t base = i * 4;
    const int m = (int)(base >> 12);
    const int u = (int)((base >> 8) & 15);
    const int o = (int)(base & 255);

    const size_t pb = ((size_t)u * 128 + m) * 256 + o;
    const size_t slab = (size_t)16 * 128 * 256;
    f32x4 s = *(const f32x4*)(part + pb);
    s += *(const f32x4*)(part + pb + slab);
    s += *(const f32x4*)(part + pb + 2 * slab);
    s += *(const f32x4*)(part + pb + 3 * slab);
    *(f32x4*)(out1 + base) = s;
}

// ---- fallback single-K state GEMM (v8, unchanged) ----
__global__ __launch_bounds__(512)
void state_gemm_fb(const float* __restrict__ X, const float* __restrict__ state,
                   const float* __restrict__ W, const float* __restrict__ Win,
                   const float* __restrict__ bias, const float* __restrict__ sr,
                   const float* __restrict__ lr, float* __restrict__ out0)
{
    const int id = blockIdx.x;
    const int u  = id & 15;
    const int nt = id >> 4;

    const int tid  = threadIdx.x;
    const int wave = tid >> 6;
    const int lane = tid & 63;
    const int l16  = lane & 15, kgl = lane >> 4;
    const int wm = wave & 3, wn = wave >> 2;

    __shared__ unsigned short As[2][128 * LDT];
    __shared__ unsigned short Bs[2][32 * LDT];

    const float sru = sr[u];
    const int col0 = nt * 32;

    const int rA = tid >> 2;
    const int cA = (tid & 3) * 16;
    const int kB = tid >> 3;
    const int nB = (tid & 7) * 4;
    const int gB = kB >> 3, kL = kB & 7;

    f32x4 rAE[4], rAO[4];
    f32x4 rBE,    rBO;

    auto ldA = [&](int s, f32x4 (&ra)[4]) {
        const int k0 = s * BK;
        const float* base = (k0 < Dsz)
            ? X     + ((size_t)rA * Usz + u) * Dsz + k0 + cA
            : state + ((size_t)rA * Usz + u) * Nsz + (k0 - Dsz) + cA;
        #pragma unroll
        for (int j = 0; j < 4; j++) ra[j] = *(const f32x4*)(base + 4 * j);
    };
    auto ldB = [&](int s, f32x4& rb) {
        const int k0 = s * BK;
        const float* base = (k0 < Dsz)
            ? Win + (size_t)u * Dsz * Nsz + (size_t)(k0 + kB) * Nsz + col0 + nB
            : W   + (size_t)u * Nsz * Nsz + (size_t)(k0 - Dsz + kB) * Nsz + col0 + nB;
        rb = *(const f32x4*)base;
    };
    auto wrA = [&](int p, f32x4 (&ra)[4]) {
        u32x4 w0, w1;
        w0[0] = pk(ra[0][0], ra[0][1]); w0[1] = pk(ra[0][2], ra[0][3]);
        w0[2] = pk(ra[1][0], ra[1][1]); w0[3] = pk(ra[1][2], ra[1][3]);
        w1[0] = pk(ra[2][0], ra[2][1]); w1[1] = pk(ra[2][2], ra[2][3]);
        w1[2] = pk(ra[3][0], ra[3][1]); w1[3] = pk(ra[3][2], ra[3][3]);
        *(u32x4*)&As[p][rA * LDT + cA]     = w0;
        *(u32x4*)&As[p][rA * LDT + cA + 8] = w1;
    };
    auto wrB = [&](int p, f32x4& rb, float sc) {
        const int c = tid & 7;
        const int go = ((gB ^ c) << 3) + kL;
        #pragma unroll
        for (int e = 0; e < 4; e++)
            Bs[p][(nB + e) * LDT + go] = bf16t(rb[e] * sc);
    };
    auto rdB = [&](int p, int kk) -> bf16x8 {
        const int n = wn * 16 + l16;
        const int go = (((kk * 4 + kgl) ^ (n >> 2)) << 3);
        return *(const bf16x8*)&Bs[p][n * LDT + go];
    };

    f32x4 acc[2] = {};
    auto comp = [&](int p) {
        #pragma unroll
        for (int kk = 0; kk < 2; kk++) {
            const bf16x8 bf = rdB(p, kk);
            #pragma unroll
            for (int mi = 0; mi < 2; mi++) {
                const bf16x8 af = *(const bf16x8*)&As[p][(wm * 32 + mi * 16 + l16) * LDT + kk * 32 + kgl * 8];
                acc[mi] = __builtin_amdgcn_mfma_f32_16x16x32_bf16(af, bf, acc[mi], 0, 0, 0);
            }
        }
    };
    auto scB = [&](int s) -> float { return (s * BK < Dsz) ? 1.f : sru; };

    ldA(0, rAE); ldB(0, rBE);
    ldA(1, rAO); ldB(1, rBO);
    wrA(0, rAE); wrB(0, rBE, scB(0));
    sync_nodrain();

    for (int s2 = 0; s2 < 10; s2++) {
        const int s = 2 * s2;
        if (s + 2 < 20) { ldA(s + 2, rAE); ldB(s + 2, rBE); }
        wrA(1, rAO); wrB(1, rBO, scB(s + 1));
        comp(0);
        sync_nodrain();
        if (s + 3 < 20) { ldA(s + 3, rAO); ldB(s + 3, rBO); }
        if (s + 2 < 20) { wrA(0, rAE); wrB(0, rBE, scB(s + 2)); }
        comp(1);
        sync_nodrain();
    }

    const int gcol = col0 + wn * 16 + l16;
    const float bi = bias[u * Nsz + gcol];
    #pragma unroll
    for (int mi = 0; mi < 2; mi++) {
        #pragma unroll
        for (int rg = 0; rg < 4; rg++) {
            const int grow = wm * 32 + mi * 16 + kgl * 4 + rg;
            const size_t idx = ((size_t)grow * Usz + u) * Nsz + gcol;
            const float th = tanhf(acc[mi][rg] + bi);
            const float lv = lr[grow * Usz + u];
            out0[idx] = (1.f - lv) * state[idx] + lv * th;
        }
    }
}

extern "C" void kernel_launch(void* const* d_in, const int* in_sizes, int n_in,
                              void* d_out, int out_size, void* d_ws, size_t ws_size,
                              hipStream_t stream)
{
    (void)in_sizes; (void)n_in; (void)out_size;
    const float* X     = (const float*)d_in[0];
    const float* state = (const float*)d_in[1];
    const float* W     = (const float*)d_in[2];
    const float* Win   = (const float*)d_in[3];
    const float* bias  = (const float*)d_in[4];
    const float* Wout  = (const float*)d_in[5];
    const float* sr    = (const float*)d_in[6];
    const float* alr   = (const float*)d_in[7];
    const float* temp  = (const float*)d_in[8];

    float* out0 = (float*)d_out;                      // (B,U,N)
    float* out1 = out0 + (size_t)Bsz * Usz * Nsz;     // (B,U,O)
    float* lr   = (float*)d_ws;                       // 8 KB

    const size_t p_off    = 8192;
    const size_t p_bytes  = (size_t)4 * 16 * 128 * 256 * 4;    // 8 MiB (out partials)
    const size_t p2_off   = p_off + p_bytes;
    const size_t p2_bytes = (size_t)2 * 128 * 16 * 1024 * 4;   // 16 MiB (state partials)
    const size_t need     = p2_off + p2_bytes;                 // ~24.1 MiB

    lr_kernel<<<Bsz, 256, 0, stream>>>(X, alr, temp, lr);

    if (ws_size >= need) {
        float* part  = (float*)((char*)d_ws + p_off);
        float* part2 = (float*)((char*)d_ws + p2_off);
        state_gemm_sk<<<1024, 512, 0, stream>>>(X, state, W, Win, sr, part2);
        state_ep<<<2048, 256, 0, stream>>>(part2, state, bias, lr, out0);
        out_gemm_fb<<<512, 512, 0, stream>>>(out0, Wout, part, 4, 1);
        out_reduce<<<512, 256, 0, stream>>>(part, out1);
    } else if (ws_size >= p_off + p_bytes) {
        float* part = (float*)((char*)d_ws + p_off);
        state_gemm_fb<<<512, 512, 0, stream>>>(X, state, W, Win, bias, sr, lr, out0);
        out_gemm_fb<<<512, 512, 0, stream>>>(out0, Wout, part, 4, 1);
        out_reduce<<<512, 256, 0, stream>>>(part, out1);
    } else {
        state_gemm_fb<<<512, 512, 0, stream>>>(X, state, W, Win, bias, sr, lr, out0);
        out_gemm_fb<<<128, 512, 0, stream>>>(out0, Wout, out1, 16, 0);
    }
}